// Round 16
// baseline (6084.012 us; speedup 1.0000x reference)
//
#include <hip/hip_runtime.h>
#include <math.h>

#define VOCAB 20000
#define EDIM  100
#define HDIM  200
#define KTAG  17
#define BATCH 128
#define TLEN  512

// ws layout (float offsets)
static const size_t PROJ_OFF = 0;              // 2 * 20000 * 800 = 32,000,000 floats
static const size_t LSTM_OFF = 32102464;       // 512*128*400 = 26,214,400
static const size_t EM_OFF   = 58316864;       // 512*128*17 = 1,114,112
// W2 (packed Whh, 80,000 float4 = 320,000 floats) overlaps the EM region:
// written by k0, read by k2, dead once k3 overwrites em.
// total = 59,430,976 floats = 237,723,904 bytes

// ---------------- K0: pack Whh — PROVEN L2-friendly layout (R6/R7/R12) ----------------
// W2f4[d][k4][e][g] = Whh_d[row = g*200+e][k = 4*k4 .. 4*k4+3], k4 in [0,50)
// Lane (e, gp) reads 32B of e's 64B line as 2 sectored 16B loads -> L2-resident
// (206MB FETCH measured). Fully-coalesced [g][e] (R8) caused 14GB HBM refetch.
__global__ __launch_bounds__(256) void k0_pack(const float* __restrict__ Whh_f,
                                               const float* __restrict__ Whh_b,
                                               float* __restrict__ ws)
{
    int i = blockIdx.x * 256 + threadIdx.x;
    if (i >= 80000) return;
    int d = i / 40000, r = i % 40000;
    int k4 = r / 800, r2 = r % 800;
    int e = r2 >> 2, g = r2 & 3;
    const float* W = d ? Whh_b : Whh_f;
    float4 v = *(const float4*)(W + (size_t)(g * 200 + e) * 200 + 4 * k4);
    ((float4*)(ws + EM_OFF))[i] = v;
}

// ---------------- K1: per-vocab input projections ----------------
__global__ __launch_bounds__(256) void k1_proj(const float* __restrict__ emb,
                                               const float* __restrict__ Wf,
                                               const float* __restrict__ Wb,
                                               float* __restrict__ ws)
{
    int blk = blockIdx.x;
    int d = blk / 313, vt = blk % 313;
    const float* Wih = d ? Wb : Wf;
    float* proj = ws + PROJ_OFF + (size_t)d * VOCAB * 800;
    __shared__ float elds[64][104];
    __shared__ float olds[64][4][26];
    int tid = threadIdx.x;
    for (int idx = tid; idx < 64 * EDIM; idx += 256) {
        int r = idx / EDIM, c = idx % EDIM;
        int v = vt * 64 + r;
        elds[r][c] = (v < VOCAB) ? emb[(size_t)v * EDIM + c] : 0.f;
    }
    __syncthreads();
    int lane = tid & 63, wq = tid >> 6;
    float4 er[25];
#pragma unroll
    for (int i = 0; i < 25; i++) er[i] = *(const float4*)&elds[lane][4 * i];
#pragma unroll 1
    for (int round = 0; round < 8; round++) {
#pragma unroll 1
        for (int m = 0; m < 25; m++) {
            int oj = wq * 200 + round * 25 + m;      // wave-uniform
            int e = oj >> 2, g = oj & 3;
            int row = __builtin_amdgcn_readfirstlane(g * HDIM + e);
            const float* wrow = Wih + (size_t)row * EDIM;
            float acc = 0.f;
#pragma unroll
            for (int i = 0; i < 25; i++) {
                float4 w4 = *(const float4*)&wrow[4 * i];
                acc += w4.x * er[i].x + w4.y * er[i].y + w4.z * er[i].z + w4.w * er[i].w;
            }
            olds[lane][wq][m] = acc;
        }
        __syncthreads();
        for (int idx = tid; idx < 6400; idx += 256) {
            int vloc = idx / 100, rem = idx % 100;
            int q = rem / 25, c = rem % 25;
            int vv = vt * 64 + vloc;
            if (vv < VOCAB) proj[(size_t)vv * 800 + q * 200 + round * 25 + c] = olds[vloc][q][c];
        }
        __syncthreads();
    }
}

// ---------------- K2: bidirectional LSTM — max W residency + streamed ring ----------------
// R15 showed residency is the working lever (9 groups resident -> -5.5%).
// This round: LDS residency grows 4 -> 9 groups (115.2 KB; total static LDS
// 121.9 KB, within the 128 KiB/wg envelope proven by the 8-phase GEMM example
// on gfx950). Resident: groups 0-4 in registers, 5-13 in LDS. Streamed:
// groups 14-49 (36/50 = 460.8 KB/step) via the proven C-level 5-deep ring.
// >80 KB LDS pins 1 wg/CU — which we already had (R15 occupancy 6.2%).
// Mapping unchanged: thread (te=tid>>1, gp=tid&1), 2 gates, k=200, B=4.
#define RING_LOAD(WA, WB) { WA = wp[0]; WB = wp[1]; wp += 800; }

#define RING_FMA(WA, WB, J)                                                   \
    {                                                                         \
        const float* hb = hrow + 4 * (J);                                     \
        float4 H0 = *(const float4*)(hb);                                     \
        float4 H1 = *(const float4*)(hb + 208);                               \
        float4 H2 = *(const float4*)(hb + 416);                               \
        float4 H3 = *(const float4*)(hb + 624);                               \
        a00 += WA.x*H0.x + WA.y*H0.y + WA.z*H0.z + WA.w*H0.w;                 \
        a01 += WA.x*H1.x + WA.y*H1.y + WA.z*H1.z + WA.w*H1.w;                 \
        a02 += WA.x*H2.x + WA.y*H2.y + WA.z*H2.z + WA.w*H2.w;                 \
        a03 += WA.x*H3.x + WA.y*H3.y + WA.z*H3.z + WA.w*H3.w;                 \
        a10 += WB.x*H0.x + WB.y*H0.y + WB.z*H0.z + WB.w*H0.w;                 \
        a11 += WB.x*H1.x + WB.y*H1.y + WB.z*H1.z + WB.w*H1.w;                 \
        a12 += WB.x*H2.x + WB.y*H2.y + WB.z*H2.z + WB.w*H2.w;                 \
        a13 += WB.x*H3.x + WB.y*H3.y + WB.z*H3.z + WB.w*H3.w;                 \
    }

#define LDS_FMA(JJ, J)                                                        \
    { float4 la = w_sh[JJ][te][gp][0], lb = w_sh[JJ][te][gp][1];              \
      RING_FMA(la, lb, J) }

__global__ __launch_bounds__(512, 2) void k2_lstm(const int* __restrict__ sentence,
                                                  const float* __restrict__ bf,
                                                  const float* __restrict__ bb,
                                                  float* __restrict__ ws)
{
    int w = blockIdx.x;               // 64 = 2 dirs x 32 batch-tiles (B=4)
    int d = w >> 5, bt = w & 31;
    int B0 = bt * 4;
    const float* bvec = d ? bb : bf;
    const float* proj = ws + PROJ_OFF + (size_t)d * VOCAB * 800;
    const float4* W2 = (const float4*)(ws + EM_OFF) + (size_t)d * 40000;
    float* lstm_out = ws + LSTM_OFF;

    __shared__ float4 w_sh[9][200][2][2];   // 115,200 B : W groups 5..13 resident
    __shared__ float h_lds[2][4][208];      //   6,656 B : h double-buffer
    // static LDS total 121,856 B (<= 128 KiB proven envelope, 160 KiB HW limit)

    int tid = threadIdx.x;
    int te = tid >> 1, gp = tid & 1;
    bool active = te < 200;

    // one-time: W groups 5..13 -> LDS (32B per thread, coalesced)
    for (int i = tid; i < 3600; i += 512) {
        int jj = i / 400, r = i % 400, te_ = r >> 1, gp_ = r & 1;
        const float4* src = W2 + ((size_t)(jj + 5) * 200 + te_) * 4 + gp_ * 2;
        w_sh[jj][te_][gp_][0] = src[0];
        w_sh[jj][te_][gp_][1] = src[1];
    }
    for (int i = tid; i < 4 * 208; i += 512) ((float*)h_lds[0])[i] = 0.f;

    float bias_i = 0.f, bias_f = 0.f, bias_g = 0.f, bias_o = 0.f;
    if (gp == 0 && active) {
        bias_i = bvec[te];
        bias_f = bvec[200 + te];
        bias_g = bvec[400 + te];
        bias_o = bvec[600 + te];
    }
    // W2 float4 index: (k4*200 + e)*4 + g ; this thread reads g = 2*gp, 2*gp+1
    const float4* wbase = W2 + ((size_t)(active ? te : 0)) * 4 + gp * 2;

    // one-time: W groups 0..4 resident in NAMED registers (40 VGPR)
    float4 r0a, r0b, r1a, r1b, r2a, r2b, r3a, r3b, r4a, r4b;
    {
        const float4* wp2 = wbase;
        r0a = wp2[0]; r0b = wp2[1]; wp2 += 800;
        r1a = wp2[0]; r1b = wp2[1]; wp2 += 800;
        r2a = wp2[0]; r2b = wp2[1]; wp2 += 800;
        r3a = wp2[0]; r3b = wp2[1]; wp2 += 800;
        r4a = wp2[0]; r4b = wp2[1];
    }
    float c0 = 0.f, c1 = 0.f, c2 = 0.f, c3 = 0.f;
    __syncthreads();

#pragma unroll 1
    for (int t = 0; t < TLEN; t++) {
        int t_eff = d ? (TLEN - 1 - t) : t;
        int p = t & 1;

        // xp gathers: token loads (wave-uniform address -> 1 line, L2-hot)
        // then proj gathers; issued at step top, consumed in the epilogue
        float4 xp0, xp1, xp2, xp3;
        if (gp == 0 && active) {
            int t0 = sentence[(size_t)(B0 + 0) * TLEN + t_eff];
            int t1 = sentence[(size_t)(B0 + 1) * TLEN + t_eff];
            int t2 = sentence[(size_t)(B0 + 2) * TLEN + t_eff];
            int t3 = sentence[(size_t)(B0 + 3) * TLEN + t_eff];
            xp0 = *(const float4*)(proj + (size_t)t0 * 800 + 4 * te);
            xp1 = *(const float4*)(proj + (size_t)t1 * 800 + 4 * te);
            xp2 = *(const float4*)(proj + (size_t)t2 * 800 + 4 * te);
            xp3 = *(const float4*)(proj + (size_t)t3 * 800 + 4 * te);
        }

        float a00 = 0.f, a01 = 0.f, a02 = 0.f, a03 = 0.f;
        float a10 = 0.f, a11 = 0.f, a12 = 0.f, a13 = 0.f;

        if (active) {
            const float* hrow = &h_lds[p][0][0];
            const float4* wp = wbase + 11200;    // streamed region starts at group 14
            float4 w0a, w0b, w1a, w1b, w2a, w2b, w3a, w3b, w4a, w4b;
            // issue the stream FIRST (latency hides under 14 resident consumes)
            RING_LOAD(w0a, w0b)                  // group 14
            RING_LOAD(w1a, w1b)                  // group 15
            RING_LOAD(w2a, w2b)                  // group 16
            RING_LOAD(w3a, w3b)                  // group 17
            RING_LOAD(w4a, w4b)                  // group 18
            // resident consumes: groups 0..4 from registers
            RING_FMA(r0a, r0b, 0)
            RING_FMA(r1a, r1b, 1)
            RING_FMA(r2a, r2b, 2)
            RING_FMA(r3a, r3b, 3)
            RING_FMA(r4a, r4b, 4)
            // resident consumes: groups 5..13 from LDS
            LDS_FMA(0, 5)
            LDS_FMA(1, 6)
            LDS_FMA(2, 7)
            LDS_FMA(3, 8)
            LDS_FMA(4, 9)
            LDS_FMA(5, 10)
            LDS_FMA(6, 11)
            LDS_FMA(7, 12)
            LDS_FMA(8, 13)
            // streamed: groups 14..49 via 5-deep ring (named slots, rule #20)
#pragma unroll 1
            for (int it = 0; it < 6; ++it) {
                int j0 = 14 + it * 5;
                RING_FMA(w0a, w0b, j0 + 0) RING_LOAD(w0a, w0b)
                RING_FMA(w1a, w1b, j0 + 1) RING_LOAD(w1a, w1b)
                RING_FMA(w2a, w2b, j0 + 2) RING_LOAD(w2a, w2b)
                RING_FMA(w3a, w3b, j0 + 3) RING_LOAD(w3a, w3b)
                RING_FMA(w4a, w4b, j0 + 4) RING_LOAD(w4a, w4b)
            }
            // tail: slots hold groups 44..48; one last load (49) then drain
            RING_FMA(w0a, w0b, 44) RING_LOAD(w0a, w0b)   // loads group 49
            RING_FMA(w1a, w1b, 45)
            RING_FMA(w2a, w2b, 46)
            RING_FMA(w3a, w3b, 47)
            RING_FMA(w4a, w4b, 48)
            RING_FMA(w0a, w0b, 49)
        }

        // pair exchange: gp0 receives (aG, aO) from its gp1 neighbor (lane+1)
        float xg0 = __shfl_xor(a00, 1), xg1 = __shfl_xor(a01, 1);
        float xg2 = __shfl_xor(a02, 1), xg3 = __shfl_xor(a03, 1);
        float xo0 = __shfl_xor(a10, 1), xo1 = __shfl_xor(a11, 1);
        float xo2 = __shfl_xor(a12, 1), xo3 = __shfl_xor(a13, 1);

        if (gp == 0 && active) {
            int pn = p ^ 1;
            float gi, gf, gg, go, sI, sF, sO, hv2;
            gi = a00 + xp0.x + bias_i;  gf = a10 + xp0.y + bias_f;
            gg = xg0 + xp0.z + bias_g;  go = xo0 + xp0.w + bias_o;
            sI = 1.f/(1.f+expf(-gi)); sF = 1.f/(1.f+expf(-gf)); sO = 1.f/(1.f+expf(-go));
            c0 = sF*c0 + sI*tanhf(gg);  hv2 = sO*tanhf(c0);
            h_lds[pn][0][te] = hv2;
            lstm_out[((size_t)t_eff * BATCH + B0 + 0) * 400 + d * 200 + te] = hv2;

            gi = a01 + xp1.x + bias_i;  gf = a11 + xp1.y + bias_f;
            gg = xg1 + xp1.z + bias_g;  go = xo1 + xp1.w + bias_o;
            sI = 1.f/(1.f+expf(-gi)); sF = 1.f/(1.f+expf(-gf)); sO = 1.f/(1.f+expf(-go));
            c1 = sF*c1 + sI*tanhf(gg);  hv2 = sO*tanhf(c1);
            h_lds[pn][1][te] = hv2;
            lstm_out[((size_t)t_eff * BATCH + B0 + 1) * 400 + d * 200 + te] = hv2;

            gi = a02 + xp2.x + bias_i;  gf = a12 + xp2.y + bias_f;
            gg = xg2 + xp2.z + bias_g;  go = xo2 + xp2.w + bias_o;
            sI = 1.f/(1.f+expf(-gi)); sF = 1.f/(1.f+expf(-gf)); sO = 1.f/(1.f+expf(-go));
            c2 = sF*c2 + sI*tanhf(gg);  hv2 = sO*tanhf(c2);
            h_lds[pn][2][te] = hv2;
            lstm_out[((size_t)t_eff * BATCH + B0 + 2) * 400 + d * 200 + te] = hv2;

            gi = a03 + xp3.x + bias_i;  gf = a13 + xp3.y + bias_f;
            gg = xg3 + xp3.z + bias_g;  go = xo3 + xp3.w + bias_o;
            sI = 1.f/(1.f+expf(-gi)); sF = 1.f/(1.f+expf(-gf)); sO = 1.f/(1.f+expf(-go));
            c3 = sF*c3 + sI*tanhf(gg);  hv2 = sO*tanhf(c3);
            h_lds[pn][3][te] = hv2;
            lstm_out[((size_t)t_eff * BATCH + B0 + 3) * 400 + d * 200 + te] = hv2;
        }
        __syncthreads();   // step t's h-writes visible before step t+1's reads
    }
}

// ---------------- K3: emissions em = lstm_out @ W_fc^T + b_fc ----------------
__global__ __launch_bounds__(256) void k3_em(const float* __restrict__ Wfc,
                                             const float* __restrict__ bfc,
                                             float* __restrict__ ws)
{
    __shared__ float llds[15][404];
    __shared__ float wlds[17][404];
    const float* lstm = ws + LSTM_OFF;
    float* em = ws + EM_OFF;
    int n0 = blockIdx.x * 15;
    int tid = threadIdx.x;
    for (int idx = tid; idx < 15 * 400; idx += 256) {
        int r = idx / 400, c = idx % 400;
        int n = n0 + r;
        llds[r][c] = (n < BATCH * TLEN) ? lstm[(size_t)n * 400 + c] : 0.f;
    }
    for (int idx = tid; idx < 17 * 400; idx += 256) {
        int r = idx / 400, c = idx % 400;
        wlds[r][c] = Wfc[r * 400 + c];
    }
    __syncthreads();
    if (tid < 255) {
        int tk = tid / 17, k = tid % 17;
        int n = n0 + tk;
        if (n < BATCH * TLEN) {
            float acc = 0.f;
#pragma unroll
            for (int i = 0; i < 100; i++) {
                float4 a  = *(const float4*)&llds[tk][4 * i];
                float4 wv = *(const float4*)&wlds[k][4 * i];
                acc += a.x * wv.x + a.y * wv.y + a.z * wv.z + a.w * wv.w;
            }
            em[(size_t)n * KTAG + k] = acc + bfc[k];
        }
    }
}

// ---------------- K4: bin_scores = mean_t(lstm_out) @ W_bin^T + b_bin ----------------
__global__ __launch_bounds__(256) void k4_bin(const float* __restrict__ Wbin,
                                              const float* __restrict__ bbin,
                                              float* __restrict__ ws,
                                              float* __restrict__ out)
{
    int b = blockIdx.x, tid = threadIdx.x;
    const float* lstm = ws + LSTM_OFF;
    __shared__ float m_lds[400];
    float a0 = 0.f, a1 = 0.f;
#pragma unroll 4
    for (int t = 0; t < TLEN; t++) {
        const float* rowp = lstm + ((size_t)t * BATCH + b) * 400;
        a0 += rowp[tid];
        if (tid < 144) a1 += rowp[256 + tid];
    }
    m_lds[tid] = a0 * (1.f / 512.f);
    if (tid < 144) m_lds[256 + tid] = a1 * (1.f / 512.f);
    __syncthreads();
    int wv = tid >> 6, lane = tid & 63;
    if (wv < 2) {
        float p = 0.f;
        for (int j = lane; j < 400; j += 64) p += m_lds[j] * Wbin[wv * 400 + j];
#pragma unroll
        for (int off = 32; off > 0; off >>= 1) p += __shfl_down(p, off);
        if (lane == 0) out[(size_t)BATCH * TLEN + b * 2 + wv] = p + bbin[wv];
    }
}

// ---------------- K5: masked Viterbi decode + traceback ----------------
__global__ __launch_bounds__(64) void k5_vit(const int* __restrict__ masks,
                                             const float* __restrict__ trans,
                                             const float* __restrict__ startv,
                                             const float* __restrict__ endv,
                                             const float* __restrict__ ws,
                                             float* __restrict__ out)
{
    int b = blockIdx.x, lane = threadIdx.x;
    const float* em = ws + EM_OFF;
    __shared__ float emlds[TLEN * KTAG];
    __shared__ unsigned char bpl[TLEN * KTAG];
    __shared__ int mlds[TLEN];
    __shared__ unsigned char tagl[TLEN];
    __shared__ float slds[KTAG];
    __shared__ float fin[KTAG];

    for (int idx = lane; idx < TLEN * KTAG; idx += 64) {
        int tt = idx / KTAG, j = idx - tt * KTAG;
        emlds[idx] = em[((size_t)tt * BATCH + b) * KTAG + j];
    }
    for (int idx = lane; idx < TLEN; idx += 64) mlds[idx] = masks[(size_t)b * TLEN + idx];
    bool on = lane < KTAG;
    float tr[KTAG];
    if (on) {
#pragma unroll
        for (int i = 0; i < KTAG; i++) tr[i] = trans[i * KTAG + lane];
    }
    __syncthreads();
    float sown = 0.f;
    if (on) { sown = startv[lane] + emlds[lane]; slds[lane] = sown; }
    __syncthreads();
#pragma unroll 1
    for (int t = 1; t < TLEN; t++) {
        int m = mlds[t];
        float ns = sown; int idx = lane;
        if (on) {
            float best = -3.4e38f; int bi = 0;
#pragma unroll
            for (int i = 0; i < KTAG; i++) {
                float vv = slds[i] + tr[i];
                if (vv > best) { best = vv; bi = i; }   // strict > => first max (matches jnp.argmax)
            }
            if (m != 0) { ns = best + emlds[t * KTAG + lane]; idx = bi; }
        }
        __syncthreads();
        if (on) { sown = ns; slds[lane] = ns; bpl[t * KTAG + lane] = (unsigned char)idx; }
        __syncthreads();
    }
    if (on) fin[lane] = sown + endv[lane];
    __syncthreads();
    if (lane == 0) {
        float bb = -3.4e38f; int bi = 0;
#pragma unroll
        for (int i = 0; i < KTAG; i++) if (fin[i] > bb) { bb = fin[i]; bi = i; }
        int cur = bi;
        tagl[TLEN - 1] = (unsigned char)cur;
        for (int t = TLEN - 1; t >= 1; t--) {
            cur = bpl[t * KTAG + cur];
            tagl[t - 1] = (unsigned char)cur;
        }
    }
    __syncthreads();
    for (int s = lane; s < TLEN; s += 64) out[(size_t)b * TLEN + s] = (float)tagl[s];
}

extern "C" void kernel_launch(void* const* d_in, const int* in_sizes, int n_in,
                              void* d_out, int out_size, void* d_ws, size_t ws_size,
                              hipStream_t stream)
{
    (void)in_sizes; (void)n_in; (void)out_size; (void)ws_size;
    const int*   sentence = (const int*)d_in[0];
    const int*   masks    = (const int*)d_in[1];
    const float* emb      = (const float*)d_in[2];
    const float* Wih_f    = (const float*)d_in[3];
    const float* Whh_f    = (const float*)d_in[4];
    const float* b_f      = (const float*)d_in[5];
    const float* Wih_b    = (const float*)d_in[6];
    const float* Whh_b    = (const float*)d_in[7];
    const float* b_b      = (const float*)d_in[8];
    const float* W_fc     = (const float*)d_in[9];
    const float* b_fc     = (const float*)d_in[10];
    const float* W_bin    = (const float*)d_in[11];
    const float* b_bin    = (const float*)d_in[12];
    const float* trans    = (const float*)d_in[13];
    const float* startv   = (const float*)d_in[14];
    const float* endv     = (const float*)d_in[15];
    float* ws  = (float*)d_ws;
    float* out = (float*)d_out;

    k0_pack<<<313, 256, 0, stream>>>(Whh_f, Whh_b, ws);
    k1_proj<<<626, 256, 0, stream>>>(emb, Wih_f, Wih_b, ws);
    k2_lstm<<<64, 512, 0, stream>>>(sentence, b_f, b_b, ws);
    k3_em<<<4370, 256, 0, stream>>>(W_fc, b_fc, ws);
    k4_bin<<<128, 256, 0, stream>>>(W_bin, b_bin, ws, out);
    k5_vit<<<128, 64, 0, stream>>>(masks, trans, startv, endv, ws, out);
}

// Round 17
// 4901.763 us; speedup vs baseline: 1.2412x; 1.2412x over previous
//
#include <hip/hip_runtime.h>
#include <math.h>

#define VOCAB 20000
#define EDIM  100
#define HDIM  200
#define KTAG  17
#define BATCH 128
#define TLEN  512

typedef float f2 __attribute__((ext_vector_type(2)));

// ws layout (float offsets)
static const size_t PROJ_OFF = 0;              // 2 * 20000 * 800 = 32,000,000 floats
static const size_t LSTM_OFF = 32102464;       // 512*128*400 = 26,214,400
static const size_t EM_OFF   = 58316864;       // 512*128*17 = 1,114,112
// W2 (packed Whh, 80,000 float4 = 320,000 floats) overlaps the EM region:
// written by k0, read by k2, dead once k3 overwrites em.
// total = 59,430,976 floats = 237,723,904 bytes

// ---------------- K0: pack Whh — PROVEN L2-friendly layout (R6/R7/R12) ----------------
// W2f4[d][k4][e][g] = Whh_d[row = g*200+e][k = 4*k4 .. 4*k4+3], k4 in [0,50)
// Lane (e, gp) reads 32B of e's 64B line as 2 sectored 16B loads -> L2-resident
// (206MB FETCH measured). Fully-coalesced [g][e] (R8) caused 14GB HBM refetch.
__global__ __launch_bounds__(256) void k0_pack(const float* __restrict__ Whh_f,
                                               const float* __restrict__ Whh_b,
                                               float* __restrict__ ws)
{
    int i = blockIdx.x * 256 + threadIdx.x;
    if (i >= 80000) return;
    int d = i / 40000, r = i % 40000;
    int k4 = r / 800, r2 = r % 800;
    int e = r2 >> 2, g = r2 & 3;
    const float* W = d ? Whh_b : Whh_f;
    float4 v = *(const float4*)(W + (size_t)(g * 200 + e) * 200 + 4 * k4);
    ((float4*)(ws + EM_OFF))[i] = v;
}

// ---------------- K1: per-vocab input projections ----------------
__global__ __launch_bounds__(256) void k1_proj(const float* __restrict__ emb,
                                               const float* __restrict__ Wf,
                                               const float* __restrict__ Wb,
                                               float* __restrict__ ws)
{
    int blk = blockIdx.x;
    int d = blk / 313, vt = blk % 313;
    const float* Wih = d ? Wb : Wf;
    float* proj = ws + PROJ_OFF + (size_t)d * VOCAB * 800;
    __shared__ float elds[64][104];
    __shared__ float olds[64][4][26];
    int tid = threadIdx.x;
    for (int idx = tid; idx < 64 * EDIM; idx += 256) {
        int r = idx / EDIM, c = idx % EDIM;
        int v = vt * 64 + r;
        elds[r][c] = (v < VOCAB) ? emb[(size_t)v * EDIM + c] : 0.f;
    }
    __syncthreads();
    int lane = tid & 63, wq = tid >> 6;
    float4 er[25];
#pragma unroll
    for (int i = 0; i < 25; i++) er[i] = *(const float4*)&elds[lane][4 * i];
#pragma unroll 1
    for (int round = 0; round < 8; round++) {
#pragma unroll 1
        for (int m = 0; m < 25; m++) {
            int oj = wq * 200 + round * 25 + m;      // wave-uniform
            int e = oj >> 2, g = oj & 3;
            int row = __builtin_amdgcn_readfirstlane(g * HDIM + e);
            const float* wrow = Wih + (size_t)row * EDIM;
            float acc = 0.f;
#pragma unroll
            for (int i = 0; i < 25; i++) {
                float4 w4 = *(const float4*)&wrow[4 * i];
                acc += w4.x * er[i].x + w4.y * er[i].y + w4.z * er[i].z + w4.w * er[i].w;
            }
            olds[lane][wq][m] = acc;
        }
        __syncthreads();
        for (int idx = tid; idx < 6400; idx += 256) {
            int vloc = idx / 100, rem = idx % 100;
            int q = rem / 25, c = rem % 25;
            int vv = vt * 64 + vloc;
            if (vv < VOCAB) proj[(size_t)vv * 800 + q * 200 + round * 25 + c] = olds[vloc][q][c];
        }
        __syncthreads();
    }
}

// ---------------- K2: bidirectional LSTM — packed-FP32 FMA + residency + ring ----------------
// R16 closed the bytes-lever (null). Counters: VALUBusy ~68% on active CUs ->
// VALU-ISSUE bound. MI355X peak FP32 needs v_pk_fma_f32 (2 FP32/lane/cyc);
// scalar FMA caps at half, and hipcc won't auto-pack. This round: k-dim packed
// f2 FMAs via __builtin_elementwise_fma (llvm.fma.v2f32 -> v_pk_fma_f32):
// 1600 -> 800 FMA instr/thread/step. Residency shifted 5reg+9LDS -> 2reg+7LDS
// (same 9 resident groups as R15-best; frees 24 VGPR for the f2 accumulators).
// Mapping unchanged: thread (te=tid>>1, gp=tid&1), 2 gates, k=200, B=4.
#define RING_LOAD(WA, WB) { WA = wp[0]; WB = wp[1]; wp += 800; }

#define RING_FMA(WA, WB, J)                                                   \
    {                                                                         \
        const float* hb = hrow + 4 * (J);                                     \
        float4 H0 = *(const float4*)(hb);                                     \
        float4 H1 = *(const float4*)(hb + 208);                               \
        float4 H2 = *(const float4*)(hb + 416);                               \
        float4 H3 = *(const float4*)(hb + 624);                               \
        f2 wal = {WA.x, WA.y}, wah = {WA.z, WA.w};                            \
        f2 wbl = {WB.x, WB.y}, wbh = {WB.z, WB.w};                            \
        f2 h0l = {H0.x, H0.y}, h0h = {H0.z, H0.w};                            \
        f2 h1l = {H1.x, H1.y}, h1h = {H1.z, H1.w};                            \
        f2 h2l = {H2.x, H2.y}, h2h = {H2.z, H2.w};                            \
        f2 h3l = {H3.x, H3.y}, h3h = {H3.z, H3.w};                            \
        A00 = __builtin_elementwise_fma(wal, h0l, A00);                       \
        A00 = __builtin_elementwise_fma(wah, h0h, A00);                       \
        A01 = __builtin_elementwise_fma(wal, h1l, A01);                       \
        A01 = __builtin_elementwise_fma(wah, h1h, A01);                       \
        A02 = __builtin_elementwise_fma(wal, h2l, A02);                       \
        A02 = __builtin_elementwise_fma(wah, h2h, A02);                       \
        A03 = __builtin_elementwise_fma(wal, h3l, A03);                       \
        A03 = __builtin_elementwise_fma(wah, h3h, A03);                       \
        A10 = __builtin_elementwise_fma(wbl, h0l, A10);                       \
        A10 = __builtin_elementwise_fma(wbh, h0h, A10);                       \
        A11 = __builtin_elementwise_fma(wbl, h1l, A11);                       \
        A11 = __builtin_elementwise_fma(wbh, h1h, A11);                       \
        A12 = __builtin_elementwise_fma(wbl, h2l, A12);                       \
        A12 = __builtin_elementwise_fma(wbh, h2h, A12);                       \
        A13 = __builtin_elementwise_fma(wbl, h3l, A13);                       \
        A13 = __builtin_elementwise_fma(wbh, h3h, A13);                       \
    }

#define LDS_FMA(JJ, J)                                                        \
    { float4 la = w_sh[JJ][te][gp][0], lb = w_sh[JJ][te][gp][1];              \
      RING_FMA(la, lb, J) }

__global__ __launch_bounds__(512, 2) void k2_lstm(const int* __restrict__ sentence,
                                                  const float* __restrict__ bf,
                                                  const float* __restrict__ bb,
                                                  float* __restrict__ ws)
{
    int w = blockIdx.x;               // 64 = 2 dirs x 32 batch-tiles (B=4)
    int d = w >> 5, bt = w & 31;
    int B0 = bt * 4;
    const float* bvec = d ? bb : bf;
    const float* proj = ws + PROJ_OFF + (size_t)d * VOCAB * 800;
    const float4* W2 = (const float4*)(ws + EM_OFF) + (size_t)d * 40000;
    float* lstm_out = ws + LSTM_OFF;

    __shared__ float4 w_sh[7][200][2][2];   // 89,600 B : W groups 2..8 resident
    __shared__ float h_lds[2][4][208];      //  6,656 B : h double-buffer
    // static LDS total 96,256 B

    int tid = threadIdx.x;
    int te = tid >> 1, gp = tid & 1;
    bool active = te < 200;

    // one-time: W groups 2..8 -> LDS (32B per thread, coalesced)
    for (int i = tid; i < 2800; i += 512) {
        int jj = i / 400, r = i % 400, te_ = r >> 1, gp_ = r & 1;
        const float4* src = W2 + ((size_t)(jj + 2) * 200 + te_) * 4 + gp_ * 2;
        w_sh[jj][te_][gp_][0] = src[0];
        w_sh[jj][te_][gp_][1] = src[1];
    }
    for (int i = tid; i < 4 * 208; i += 512) ((float*)h_lds[0])[i] = 0.f;

    float bias_i = 0.f, bias_f = 0.f, bias_g = 0.f, bias_o = 0.f;
    if (gp == 0 && active) {
        bias_i = bvec[te];
        bias_f = bvec[200 + te];
        bias_g = bvec[400 + te];
        bias_o = bvec[600 + te];
    }
    // W2 float4 index: (k4*200 + e)*4 + g ; this thread reads g = 2*gp, 2*gp+1
    const float4* wbase = W2 + ((size_t)(active ? te : 0)) * 4 + gp * 2;

    // one-time: W groups 0..1 resident in NAMED registers (16 VGPR)
    float4 r0a, r0b, r1a, r1b;
    {
        const float4* wp2 = wbase;
        r0a = wp2[0]; r0b = wp2[1]; wp2 += 800;
        r1a = wp2[0]; r1b = wp2[1];
    }
    float c0 = 0.f, c1 = 0.f, c2 = 0.f, c3 = 0.f;
    __syncthreads();

#pragma unroll 1
    for (int t = 0; t < TLEN; t++) {
        int t_eff = d ? (TLEN - 1 - t) : t;
        int p = t & 1;

        // xp gathers: token loads (wave-uniform address -> 1 line, L2-hot)
        // then proj gathers; issued at step top, consumed in the epilogue
        float4 xp0, xp1, xp2, xp3;
        if (gp == 0 && active) {
            int t0 = sentence[(size_t)(B0 + 0) * TLEN + t_eff];
            int t1 = sentence[(size_t)(B0 + 1) * TLEN + t_eff];
            int t2 = sentence[(size_t)(B0 + 2) * TLEN + t_eff];
            int t3 = sentence[(size_t)(B0 + 3) * TLEN + t_eff];
            xp0 = *(const float4*)(proj + (size_t)t0 * 800 + 4 * te);
            xp1 = *(const float4*)(proj + (size_t)t1 * 800 + 4 * te);
            xp2 = *(const float4*)(proj + (size_t)t2 * 800 + 4 * te);
            xp3 = *(const float4*)(proj + (size_t)t3 * 800 + 4 * te);
        }

        f2 A00 = {0.f, 0.f}, A01 = {0.f, 0.f}, A02 = {0.f, 0.f}, A03 = {0.f, 0.f};
        f2 A10 = {0.f, 0.f}, A11 = {0.f, 0.f}, A12 = {0.f, 0.f}, A13 = {0.f, 0.f};

        if (active) {
            const float* hrow = &h_lds[p][0][0];
            const float4* wp = wbase + 7200;     // streamed region starts at group 9
            float4 w0a, w0b, w1a, w1b, w2a, w2b, w3a, w3b, w4a, w4b;
            // issue the stream FIRST (latency hides under 9 resident consumes)
            RING_LOAD(w0a, w0b)                  // group 9
            RING_LOAD(w1a, w1b)                  // group 10
            RING_LOAD(w2a, w2b)                  // group 11
            RING_LOAD(w3a, w3b)                  // group 12
            RING_LOAD(w4a, w4b)                  // group 13
            // resident consumes: groups 0..1 from registers
            RING_FMA(r0a, r0b, 0)
            RING_FMA(r1a, r1b, 1)
            // resident consumes: groups 2..8 from LDS
            LDS_FMA(0, 2)
            LDS_FMA(1, 3)
            LDS_FMA(2, 4)
            LDS_FMA(3, 5)
            LDS_FMA(4, 6)
            LDS_FMA(5, 7)
            LDS_FMA(6, 8)
            // streamed: groups 9..49 via 5-deep ring (named slots, rule #20)
#pragma unroll 1
            for (int it = 0; it < 7; ++it) {
                int j0 = 9 + it * 5;
                RING_FMA(w0a, w0b, j0 + 0) RING_LOAD(w0a, w0b)
                RING_FMA(w1a, w1b, j0 + 1) RING_LOAD(w1a, w1b)
                RING_FMA(w2a, w2b, j0 + 2) RING_LOAD(w2a, w2b)
                RING_FMA(w3a, w3b, j0 + 3) RING_LOAD(w3a, w3b)
                RING_FMA(w4a, w4b, j0 + 4) RING_LOAD(w4a, w4b)
            }
            // tail: slots hold groups 44..48; one last load (49) then drain
            RING_FMA(w0a, w0b, 44) RING_LOAD(w0a, w0b)   // loads group 49
            RING_FMA(w1a, w1b, 45)
            RING_FMA(w2a, w2b, 46)
            RING_FMA(w3a, w3b, 47)
            RING_FMA(w4a, w4b, 48)
            RING_FMA(w0a, w0b, 49)
        }

        // horizontal reduce of packed accumulators, then pair exchange
        float a00 = A00.x + A00.y, a01 = A01.x + A01.y;
        float a02 = A02.x + A02.y, a03 = A03.x + A03.y;
        float a10 = A10.x + A10.y, a11 = A11.x + A11.y;
        float a12 = A12.x + A12.y, a13 = A13.x + A13.y;
        float xg0 = __shfl_xor(a00, 1), xg1 = __shfl_xor(a01, 1);
        float xg2 = __shfl_xor(a02, 1), xg3 = __shfl_xor(a03, 1);
        float xo0 = __shfl_xor(a10, 1), xo1 = __shfl_xor(a11, 1);
        float xo2 = __shfl_xor(a12, 1), xo3 = __shfl_xor(a13, 1);

        if (gp == 0 && active) {
            int pn = p ^ 1;
            float gi, gf, gg, go, sI, sF, sO, hv2;
            gi = a00 + xp0.x + bias_i;  gf = a10 + xp0.y + bias_f;
            gg = xg0 + xp0.z + bias_g;  go = xo0 + xp0.w + bias_o;
            sI = 1.f/(1.f+expf(-gi)); sF = 1.f/(1.f+expf(-gf)); sO = 1.f/(1.f+expf(-go));
            c0 = sF*c0 + sI*tanhf(gg);  hv2 = sO*tanhf(c0);
            h_lds[pn][0][te] = hv2;
            lstm_out[((size_t)t_eff * BATCH + B0 + 0) * 400 + d * 200 + te] = hv2;

            gi = a01 + xp1.x + bias_i;  gf = a11 + xp1.y + bias_f;
            gg = xg1 + xp1.z + bias_g;  go = xo1 + xp1.w + bias_o;
            sI = 1.f/(1.f+expf(-gi)); sF = 1.f/(1.f+expf(-gf)); sO = 1.f/(1.f+expf(-go));
            c1 = sF*c1 + sI*tanhf(gg);  hv2 = sO*tanhf(c1);
            h_lds[pn][1][te] = hv2;
            lstm_out[((size_t)t_eff * BATCH + B0 + 1) * 400 + d * 200 + te] = hv2;

            gi = a02 + xp2.x + bias_i;  gf = a12 + xp2.y + bias_f;
            gg = xg2 + xp2.z + bias_g;  go = xo2 + xp2.w + bias_o;
            sI = 1.f/(1.f+expf(-gi)); sF = 1.f/(1.f+expf(-gf)); sO = 1.f/(1.f+expf(-go));
            c2 = sF*c2 + sI*tanhf(gg);  hv2 = sO*tanhf(c2);
            h_lds[pn][2][te] = hv2;
            lstm_out[((size_t)t_eff * BATCH + B0 + 2) * 400 + d * 200 + te] = hv2;

            gi = a03 + xp3.x + bias_i;  gf = a13 + xp3.y + bias_f;
            gg = xg3 + xp3.z + bias_g;  go = xo3 + xp3.w + bias_o;
            sI = 1.f/(1.f+expf(-gi)); sF = 1.f/(1.f+expf(-gf)); sO = 1.f/(1.f+expf(-go));
            c3 = sF*c3 + sI*tanhf(gg);  hv2 = sO*tanhf(c3);
            h_lds[pn][3][te] = hv2;
            lstm_out[((size_t)t_eff * BATCH + B0 + 3) * 400 + d * 200 + te] = hv2;
        }
        __syncthreads();   // step t's h-writes visible before step t+1's reads
    }
}

// ---------------- K3: emissions em = lstm_out @ W_fc^T + b_fc ----------------
__global__ __launch_bounds__(256) void k3_em(const float* __restrict__ Wfc,
                                             const float* __restrict__ bfc,
                                             float* __restrict__ ws)
{
    __shared__ float llds[15][404];
    __shared__ float wlds[17][404];
    const float* lstm = ws + LSTM_OFF;
    float* em = ws + EM_OFF;
    int n0 = blockIdx.x * 15;
    int tid = threadIdx.x;
    for (int idx = tid; idx < 15 * 400; idx += 256) {
        int r = idx / 400, c = idx % 400;
        int n = n0 + r;
        llds[r][c] = (n < BATCH * TLEN) ? lstm[(size_t)n * 400 + c] : 0.f;
    }
    for (int idx = tid; idx < 17 * 400; idx += 256) {
        int r = idx / 400, c = idx % 400;
        wlds[r][c] = Wfc[r * 400 + c];
    }
    __syncthreads();
    if (tid < 255) {
        int tk = tid / 17, k = tid % 17;
        int n = n0 + tk;
        if (n < BATCH * TLEN) {
            float acc = 0.f;
#pragma unroll
            for (int i = 0; i < 100; i++) {
                float4 a  = *(const float4*)&llds[tk][4 * i];
                float4 wv = *(const float4*)&wlds[k][4 * i];
                acc += a.x * wv.x + a.y * wv.y + a.z * wv.z + a.w * wv.w;
            }
            em[(size_t)n * KTAG + k] = acc + bfc[k];
        }
    }
}

// ---------------- K4: bin_scores = mean_t(lstm_out) @ W_bin^T + b_bin ----------------
__global__ __launch_bounds__(256) void k4_bin(const float* __restrict__ Wbin,
                                              const float* __restrict__ bbin,
                                              float* __restrict__ ws,
                                              float* __restrict__ out)
{
    int b = blockIdx.x, tid = threadIdx.x;
    const float* lstm = ws + LSTM_OFF;
    __shared__ float m_lds[400];
    float a0 = 0.f, a1 = 0.f;
#pragma unroll 4
    for (int t = 0; t < TLEN; t++) {
        const float* rowp = lstm + ((size_t)t * BATCH + b) * 400;
        a0 += rowp[tid];
        if (tid < 144) a1 += rowp[256 + tid];
    }
    m_lds[tid] = a0 * (1.f / 512.f);
    if (tid < 144) m_lds[256 + tid] = a1 * (1.f / 512.f);
    __syncthreads();
    int wv = tid >> 6, lane = tid & 63;
    if (wv < 2) {
        float p = 0.f;
        for (int j = lane; j < 400; j += 64) p += m_lds[j] * Wbin[wv * 400 + j];
#pragma unroll
        for (int off = 32; off > 0; off >>= 1) p += __shfl_down(p, off);
        if (lane == 0) out[(size_t)BATCH * TLEN + b * 2 + wv] = p + bbin[wv];
    }
}

// ---------------- K5: masked Viterbi decode + traceback ----------------
__global__ __launch_bounds__(64) void k5_vit(const int* __restrict__ masks,
                                             const float* __restrict__ trans,
                                             const float* __restrict__ startv,
                                             const float* __restrict__ endv,
                                             const float* __restrict__ ws,
                                             float* __restrict__ out)
{
    int b = blockIdx.x, lane = threadIdx.x;
    const float* em = ws + EM_OFF;
    __shared__ float emlds[TLEN * KTAG];
    __shared__ unsigned char bpl[TLEN * KTAG];
    __shared__ int mlds[TLEN];
    __shared__ unsigned char tagl[TLEN];
    __shared__ float slds[KTAG];
    __shared__ float fin[KTAG];

    for (int idx = lane; idx < TLEN * KTAG; idx += 64) {
        int tt = idx / KTAG, j = idx - tt * KTAG;
        emlds[idx] = em[((size_t)tt * BATCH + b) * KTAG + j];
    }
    for (int idx = lane; idx < TLEN; idx += 64) mlds[idx] = masks[(size_t)b * TLEN + idx];
    bool on = lane < KTAG;
    float tr[KTAG];
    if (on) {
#pragma unroll
        for (int i = 0; i < KTAG; i++) tr[i] = trans[i * KTAG + lane];
    }
    __syncthreads();
    float sown = 0.f;
    if (on) { sown = startv[lane] + emlds[lane]; slds[lane] = sown; }
    __syncthreads();
#pragma unroll 1
    for (int t = 1; t < TLEN; t++) {
        int m = mlds[t];
        float ns = sown; int idx = lane;
        if (on) {
            float best = -3.4e38f; int bi = 0;
#pragma unroll
            for (int i = 0; i < KTAG; i++) {
                float vv = slds[i] + tr[i];
                if (vv > best) { best = vv; bi = i; }   // strict > => first max (matches jnp.argmax)
            }
            if (m != 0) { ns = best + emlds[t * KTAG + lane]; idx = bi; }
        }
        __syncthreads();
        if (on) { sown = ns; slds[lane] = ns; bpl[t * KTAG + lane] = (unsigned char)idx; }
        __syncthreads();
    }
    if (on) fin[lane] = sown + endv[lane];
    __syncthreads();
    if (lane == 0) {
        float bb = -3.4e38f; int bi = 0;
#pragma unroll
        for (int i = 0; i < KTAG; i++) if (fin[i] > bb) { bb = fin[i]; bi = i; }
        int cur = bi;
        tagl[TLEN - 1] = (unsigned char)cur;
        for (int t = TLEN - 1; t >= 1; t--) {
            cur = bpl[t * KTAG + cur];
            tagl[t - 1] = (unsigned char)cur;
        }
    }
    __syncthreads();
    for (int s = lane; s < TLEN; s += 64) out[(size_t)b * TLEN + s] = (float)tagl[s];
}

extern "C" void kernel_launch(void* const* d_in, const int* in_sizes, int n_in,
                              void* d_out, int out_size, void* d_ws, size_t ws_size,
                              hipStream_t stream)
{
    (void)in_sizes; (void)n_in; (void)out_size; (void)ws_size;
    const int*   sentence = (const int*)d_in[0];
    const int*   masks    = (const int*)d_in[1];
    const float* emb      = (const float*)d_in[2];
    const float* Wih_f    = (const float*)d_in[3];
    const float* Whh_f    = (const float*)d_in[4];
    const float* b_f      = (const float*)d_in[5];
    const float* Wih_b    = (const float*)d_in[6];
    const float* Whh_b    = (const float*)d_in[7];
    const float* b_b      = (const float*)d_in[8];
    const float* W_fc     = (const float*)d_in[9];
    const float* b_fc     = (const float*)d_in[10];
    const float* W_bin    = (const float*)d_in[11];
    const float* b_bin    = (const float*)d_in[12];
    const float* trans    = (const float*)d_in[13];
    const float* startv   = (const float*)d_in[14];
    const float* endv     = (const float*)d_in[15];
    float* ws  = (float*)d_ws;
    float* out = (float*)d_out;

    k0_pack<<<313, 256, 0, stream>>>(Whh_f, Whh_b, ws);
    k1_proj<<<626, 256, 0, stream>>>(emb, Wih_f, Wih_b, ws);
    k2_lstm<<<64, 512, 0, stream>>>(sentence, b_f, b_b, ws);
    k3_em<<<4370, 256, 0, stream>>>(W_fc, b_fc, ws);
    k4_bin<<<128, 256, 0, stream>>>(W_bin, b_bin, ws, out);
    k5_vit<<<128, 64, 0, stream>>>(masks, trans, startv, endv, ws, out);
}

// Round 18
// 4740.961 us; speedup vs baseline: 1.2833x; 1.0339x over previous
//
#include <hip/hip_runtime.h>
#include <math.h>

#define VOCAB 20000
#define EDIM  100
#define HDIM  200
#define KTAG  17
#define BATCH 128
#define TLEN  512

typedef float f2 __attribute__((ext_vector_type(2)));

// ws layout (float offsets)
static const size_t PROJ_OFF = 0;              // 2 * 20000 * 800 = 32,000,000 floats
static const size_t LSTM_OFF = 32102464;       // 512*128*400 = 26,214,400
static const size_t EM_OFF   = 58316864;       // 512*128*17 = 1,114,112
// W2 (packed Whh, 80,000 float4 = 320,000 floats) overlaps the EM region:
// written by k0, read by k2, dead once k3 overwrites em.
// total = 59,430,976 floats = 237,723,904 bytes

// ---------------- K0: pack Whh — PROVEN L2-friendly layout (R6/R7/R12) ----------------
// W2f4[d][k4][e][g] = Whh_d[row = g*200+e][k = 4*k4 .. 4*k4+3], k4 in [0,50)
// Lane (e, gp) reads 32B of e's 64B line as 2 sectored 16B loads -> L2-resident
// (206MB FETCH measured). Fully-coalesced [g][e] (R8) caused 14GB HBM refetch.
__global__ __launch_bounds__(256) void k0_pack(const float* __restrict__ Whh_f,
                                               const float* __restrict__ Whh_b,
                                               float* __restrict__ ws)
{
    int i = blockIdx.x * 256 + threadIdx.x;
    if (i >= 80000) return;
    int d = i / 40000, r = i % 40000;
    int k4 = r / 800, r2 = r % 800;
    int e = r2 >> 2, g = r2 & 3;
    const float* W = d ? Whh_b : Whh_f;
    float4 v = *(const float4*)(W + (size_t)(g * 200 + e) * 200 + 4 * k4);
    ((float4*)(ws + EM_OFF))[i] = v;
}

// ---------------- K1: per-vocab input projections ----------------
__global__ __launch_bounds__(256) void k1_proj(const float* __restrict__ emb,
                                               const float* __restrict__ Wf,
                                               const float* __restrict__ Wb,
                                               float* __restrict__ ws)
{
    int blk = blockIdx.x;
    int d = blk / 313, vt = blk % 313;
    const float* Wih = d ? Wb : Wf;
    float* proj = ws + PROJ_OFF + (size_t)d * VOCAB * 800;
    __shared__ float elds[64][104];
    __shared__ float olds[64][4][26];
    int tid = threadIdx.x;
    for (int idx = tid; idx < 64 * EDIM; idx += 256) {
        int r = idx / EDIM, c = idx % EDIM;
        int v = vt * 64 + r;
        elds[r][c] = (v < VOCAB) ? emb[(size_t)v * EDIM + c] : 0.f;
    }
    __syncthreads();
    int lane = tid & 63, wq = tid >> 6;
    float4 er[25];
#pragma unroll
    for (int i = 0; i < 25; i++) er[i] = *(const float4*)&elds[lane][4 * i];
#pragma unroll 1
    for (int round = 0; round < 8; round++) {
#pragma unroll 1
        for (int m = 0; m < 25; m++) {
            int oj = wq * 200 + round * 25 + m;      // wave-uniform
            int e = oj >> 2, g = oj & 3;
            int row = __builtin_amdgcn_readfirstlane(g * HDIM + e);
            const float* wrow = Wih + (size_t)row * EDIM;
            float acc = 0.f;
#pragma unroll
            for (int i = 0; i < 25; i++) {
                float4 w4 = *(const float4*)&wrow[4 * i];
                acc += w4.x * er[i].x + w4.y * er[i].y + w4.z * er[i].z + w4.w * er[i].w;
            }
            olds[lane][wq][m] = acc;
        }
        __syncthreads();
        for (int idx = tid; idx < 6400; idx += 256) {
            int vloc = idx / 100, rem = idx % 100;
            int q = rem / 25, c = rem % 25;
            int vv = vt * 64 + vloc;
            if (vv < VOCAB) proj[(size_t)vv * 800 + q * 200 + round * 25 + c] = olds[vloc][q][c];
        }
        __syncthreads();
    }
}

// ---------------- K2: bidirectional LSTM — packed FMA + MAX residency + ring ----------------
// R17 proved packed v_pk_fma_f32 was the VALU lever (-21%); with VALU lighter
// the stream re-binds (effective rate rose 57->65 GB/s/CU). R16's residency
// increase was null UNDER scalar FMA (VALU-bound); re-apply it now:
// resident = groups 0-4 in registers (40 VGPR) + 5-13 in LDS (115.2 KB);
// streamed = groups 14-49 (36/50 = 460.8 KB/step) via the C-level 5-deep ring.
// This is R16-geometry x R17-FMA — both individually verified.
// Mapping unchanged: thread (te=tid>>1, gp=tid&1), 2 gates, k=200, B=4.
#define RING_LOAD(WA, WB) { WA = wp[0]; WB = wp[1]; wp += 800; }

#define RING_FMA(WA, WB, J)                                                   \
    {                                                                         \
        const float* hb = hrow + 4 * (J);                                     \
        float4 H0 = *(const float4*)(hb);                                     \
        float4 H1 = *(const float4*)(hb + 208);                               \
        float4 H2 = *(const float4*)(hb + 416);                               \
        float4 H3 = *(const float4*)(hb + 624);                               \
        f2 wal = {WA.x, WA.y}, wah = {WA.z, WA.w};                            \
        f2 wbl = {WB.x, WB.y}, wbh = {WB.z, WB.w};                            \
        f2 h0l = {H0.x, H0.y}, h0h = {H0.z, H0.w};                            \
        f2 h1l = {H1.x, H1.y}, h1h = {H1.z, H1.w};                            \
        f2 h2l = {H2.x, H2.y}, h2h = {H2.z, H2.w};                            \
        f2 h3l = {H3.x, H3.y}, h3h = {H3.z, H3.w};                            \
        A00 = __builtin_elementwise_fma(wal, h0l, A00);                       \
        A00 = __builtin_elementwise_fma(wah, h0h, A00);                       \
        A01 = __builtin_elementwise_fma(wal, h1l, A01);                       \
        A01 = __builtin_elementwise_fma(wah, h1h, A01);                       \
        A02 = __builtin_elementwise_fma(wal, h2l, A02);                       \
        A02 = __builtin_elementwise_fma(wah, h2h, A02);                       \
        A03 = __builtin_elementwise_fma(wal, h3l, A03);                       \
        A03 = __builtin_elementwise_fma(wah, h3h, A03);                       \
        A10 = __builtin_elementwise_fma(wbl, h0l, A10);                       \
        A10 = __builtin_elementwise_fma(wbh, h0h, A10);                       \
        A11 = __builtin_elementwise_fma(wbl, h1l, A11);                       \
        A11 = __builtin_elementwise_fma(wbh, h1h, A11);                       \
        A12 = __builtin_elementwise_fma(wbl, h2l, A12);                       \
        A12 = __builtin_elementwise_fma(wbh, h2h, A12);                       \
        A13 = __builtin_elementwise_fma(wbl, h3l, A13);                       \
        A13 = __builtin_elementwise_fma(wbh, h3h, A13);                       \
    }

#define LDS_FMA(JJ, J)                                                        \
    { float4 la = w_sh[JJ][te][gp][0], lb = w_sh[JJ][te][gp][1];              \
      RING_FMA(la, lb, J) }

__global__ __launch_bounds__(512, 2) void k2_lstm(const int* __restrict__ sentence,
                                                  const float* __restrict__ bf,
                                                  const float* __restrict__ bb,
                                                  float* __restrict__ ws)
{
    int w = blockIdx.x;               // 64 = 2 dirs x 32 batch-tiles (B=4)
    int d = w >> 5, bt = w & 31;
    int B0 = bt * 4;
    const float* bvec = d ? bb : bf;
    const float* proj = ws + PROJ_OFF + (size_t)d * VOCAB * 800;
    const float4* W2 = (const float4*)(ws + EM_OFF) + (size_t)d * 40000;
    float* lstm_out = ws + LSTM_OFF;

    __shared__ float4 w_sh[9][200][2][2];   // 115,200 B : W groups 5..13 resident
    __shared__ float h_lds[2][4][208];      //   6,656 B : h double-buffer
    // static LDS total 121,856 B (ran fine in R16; 160 KiB HW limit)

    int tid = threadIdx.x;
    int te = tid >> 1, gp = tid & 1;
    bool active = te < 200;

    // one-time: W groups 5..13 -> LDS (32B per thread, coalesced)
    for (int i = tid; i < 3600; i += 512) {
        int jj = i / 400, r = i % 400, te_ = r >> 1, gp_ = r & 1;
        const float4* src = W2 + ((size_t)(jj + 5) * 200 + te_) * 4 + gp_ * 2;
        w_sh[jj][te_][gp_][0] = src[0];
        w_sh[jj][te_][gp_][1] = src[1];
    }
    for (int i = tid; i < 4 * 208; i += 512) ((float*)h_lds[0])[i] = 0.f;

    float bias_i = 0.f, bias_f = 0.f, bias_g = 0.f, bias_o = 0.f;
    if (gp == 0 && active) {
        bias_i = bvec[te];
        bias_f = bvec[200 + te];
        bias_g = bvec[400 + te];
        bias_o = bvec[600 + te];
    }
    // W2 float4 index: (k4*200 + e)*4 + g ; this thread reads g = 2*gp, 2*gp+1
    const float4* wbase = W2 + ((size_t)(active ? te : 0)) * 4 + gp * 2;

    // one-time: W groups 0..4 resident in NAMED registers (40 VGPR)
    float4 r0a, r0b, r1a, r1b, r2a, r2b, r3a, r3b, r4a, r4b;
    {
        const float4* wp2 = wbase;
        r0a = wp2[0]; r0b = wp2[1]; wp2 += 800;
        r1a = wp2[0]; r1b = wp2[1]; wp2 += 800;
        r2a = wp2[0]; r2b = wp2[1]; wp2 += 800;
        r3a = wp2[0]; r3b = wp2[1]; wp2 += 800;
        r4a = wp2[0]; r4b = wp2[1];
    }
    float c0 = 0.f, c1 = 0.f, c2 = 0.f, c3 = 0.f;
    __syncthreads();

#pragma unroll 1
    for (int t = 0; t < TLEN; t++) {
        int t_eff = d ? (TLEN - 1 - t) : t;
        int p = t & 1;

        // xp gathers: token loads (wave-uniform address -> 1 line, L2-hot)
        // then proj gathers; issued at step top, consumed in the epilogue
        float4 xp0, xp1, xp2, xp3;
        if (gp == 0 && active) {
            int t0 = sentence[(size_t)(B0 + 0) * TLEN + t_eff];
            int t1 = sentence[(size_t)(B0 + 1) * TLEN + t_eff];
            int t2 = sentence[(size_t)(B0 + 2) * TLEN + t_eff];
            int t3 = sentence[(size_t)(B0 + 3) * TLEN + t_eff];
            xp0 = *(const float4*)(proj + (size_t)t0 * 800 + 4 * te);
            xp1 = *(const float4*)(proj + (size_t)t1 * 800 + 4 * te);
            xp2 = *(const float4*)(proj + (size_t)t2 * 800 + 4 * te);
            xp3 = *(const float4*)(proj + (size_t)t3 * 800 + 4 * te);
        }

        f2 A00 = {0.f, 0.f}, A01 = {0.f, 0.f}, A02 = {0.f, 0.f}, A03 = {0.f, 0.f};
        f2 A10 = {0.f, 0.f}, A11 = {0.f, 0.f}, A12 = {0.f, 0.f}, A13 = {0.f, 0.f};

        if (active) {
            const float* hrow = &h_lds[p][0][0];
            const float4* wp = wbase + 11200;    // streamed region starts at group 14
            float4 w0a, w0b, w1a, w1b, w2a, w2b, w3a, w3b, w4a, w4b;
            // issue the stream FIRST (latency hides under 14 resident consumes)
            RING_LOAD(w0a, w0b)                  // group 14
            RING_LOAD(w1a, w1b)                  // group 15
            RING_LOAD(w2a, w2b)                  // group 16
            RING_LOAD(w3a, w3b)                  // group 17
            RING_LOAD(w4a, w4b)                  // group 18
            // resident consumes: groups 0..4 from registers
            RING_FMA(r0a, r0b, 0)
            RING_FMA(r1a, r1b, 1)
            RING_FMA(r2a, r2b, 2)
            RING_FMA(r3a, r3b, 3)
            RING_FMA(r4a, r4b, 4)
            // resident consumes: groups 5..13 from LDS
            LDS_FMA(0, 5)
            LDS_FMA(1, 6)
            LDS_FMA(2, 7)
            LDS_FMA(3, 8)
            LDS_FMA(4, 9)
            LDS_FMA(5, 10)
            LDS_FMA(6, 11)
            LDS_FMA(7, 12)
            LDS_FMA(8, 13)
            // streamed: groups 14..49 via 5-deep ring (named slots, rule #20)
#pragma unroll 1
            for (int it = 0; it < 6; ++it) {
                int j0 = 14 + it * 5;
                RING_FMA(w0a, w0b, j0 + 0) RING_LOAD(w0a, w0b)
                RING_FMA(w1a, w1b, j0 + 1) RING_LOAD(w1a, w1b)
                RING_FMA(w2a, w2b, j0 + 2) RING_LOAD(w2a, w2b)
                RING_FMA(w3a, w3b, j0 + 3) RING_LOAD(w3a, w3b)
                RING_FMA(w4a, w4b, j0 + 4) RING_LOAD(w4a, w4b)
            }
            // tail: slots hold groups 44..48; one last load (49) then drain
            RING_FMA(w0a, w0b, 44) RING_LOAD(w0a, w0b)   // loads group 49
            RING_FMA(w1a, w1b, 45)
            RING_FMA(w2a, w2b, 46)
            RING_FMA(w3a, w3b, 47)
            RING_FMA(w4a, w4b, 48)
            RING_FMA(w0a, w0b, 49)
        }

        // horizontal reduce of packed accumulators, then pair exchange
        float a00 = A00.x + A00.y, a01 = A01.x + A01.y;
        float a02 = A02.x + A02.y, a03 = A03.x + A03.y;
        float a10 = A10.x + A10.y, a11 = A11.x + A11.y;
        float a12 = A12.x + A12.y, a13 = A13.x + A13.y;
        float xg0 = __shfl_xor(a00, 1), xg1 = __shfl_xor(a01, 1);
        float xg2 = __shfl_xor(a02, 1), xg3 = __shfl_xor(a03, 1);
        float xo0 = __shfl_xor(a10, 1), xo1 = __shfl_xor(a11, 1);
        float xo2 = __shfl_xor(a12, 1), xo3 = __shfl_xor(a13, 1);

        if (gp == 0 && active) {
            int pn = p ^ 1;
            float gi, gf, gg, go, sI, sF, sO, hv2;
            gi = a00 + xp0.x + bias_i;  gf = a10 + xp0.y + bias_f;
            gg = xg0 + xp0.z + bias_g;  go = xo0 + xp0.w + bias_o;
            sI = 1.f/(1.f+expf(-gi)); sF = 1.f/(1.f+expf(-gf)); sO = 1.f/(1.f+expf(-go));
            c0 = sF*c0 + sI*tanhf(gg);  hv2 = sO*tanhf(c0);
            h_lds[pn][0][te] = hv2;
            lstm_out[((size_t)t_eff * BATCH + B0 + 0) * 400 + d * 200 + te] = hv2;

            gi = a01 + xp1.x + bias_i;  gf = a11 + xp1.y + bias_f;
            gg = xg1 + xp1.z + bias_g;  go = xo1 + xp1.w + bias_o;
            sI = 1.f/(1.f+expf(-gi)); sF = 1.f/(1.f+expf(-gf)); sO = 1.f/(1.f+expf(-go));
            c1 = sF*c1 + sI*tanhf(gg);  hv2 = sO*tanhf(c1);
            h_lds[pn][1][te] = hv2;
            lstm_out[((size_t)t_eff * BATCH + B0 + 1) * 400 + d * 200 + te] = hv2;

            gi = a02 + xp2.x + bias_i;  gf = a12 + xp2.y + bias_f;
            gg = xg2 + xp2.z + bias_g;  go = xo2 + xp2.w + bias_o;
            sI = 1.f/(1.f+expf(-gi)); sF = 1.f/(1.f+expf(-gf)); sO = 1.f/(1.f+expf(-go));
            c2 = sF*c2 + sI*tanhf(gg);  hv2 = sO*tanhf(c2);
            h_lds[pn][2][te] = hv2;
            lstm_out[((size_t)t_eff * BATCH + B0 + 2) * 400 + d * 200 + te] = hv2;

            gi = a03 + xp3.x + bias_i;  gf = a13 + xp3.y + bias_f;
            gg = xg3 + xp3.z + bias_g;  go = xo3 + xp3.w + bias_o;
            sI = 1.f/(1.f+expf(-gi)); sF = 1.f/(1.f+expf(-gf)); sO = 1.f/(1.f+expf(-go));
            c3 = sF*c3 + sI*tanhf(gg);  hv2 = sO*tanhf(c3);
            h_lds[pn][3][te] = hv2;
            lstm_out[((size_t)t_eff * BATCH + B0 + 3) * 400 + d * 200 + te] = hv2;
        }
        __syncthreads();   // step t's h-writes visible before step t+1's reads
    }
}

// ---------------- K3: emissions em = lstm_out @ W_fc^T + b_fc ----------------
__global__ __launch_bounds__(256) void k3_em(const float* __restrict__ Wfc,
                                             const float* __restrict__ bfc,
                                             float* __restrict__ ws)
{
    __shared__ float llds[15][404];
    __shared__ float wlds[17][404];
    const float* lstm = ws + LSTM_OFF;
    float* em = ws + EM_OFF;
    int n0 = blockIdx.x * 15;
    int tid = threadIdx.x;
    for (int idx = tid; idx < 15 * 400; idx += 256) {
        int r = idx / 400, c = idx % 400;
        int n = n0 + r;
        llds[r][c] = (n < BATCH * TLEN) ? lstm[(size_t)n * 400 + c] : 0.f;
    }
    for (int idx = tid; idx < 17 * 400; idx += 256) {
        int r = idx / 400, c = idx % 400;
        wlds[r][c] = Wfc[r * 400 + c];
    }
    __syncthreads();
    if (tid < 255) {
        int tk = tid / 17, k = tid % 17;
        int n = n0 + tk;
        if (n < BATCH * TLEN) {
            float acc = 0.f;
#pragma unroll
            for (int i = 0; i < 100; i++) {
                float4 a  = *(const float4*)&llds[tk][4 * i];
                float4 wv = *(const float4*)&wlds[k][4 * i];
                acc += a.x * wv.x + a.y * wv.y + a.z * wv.z + a.w * wv.w;
            }
            em[(size_t)n * KTAG + k] = acc + bfc[k];
        }
    }
}

// ---------------- K4: bin_scores = mean_t(lstm_out) @ W_bin^T + b_bin ----------------
__global__ __launch_bounds__(256) void k4_bin(const float* __restrict__ Wbin,
                                              const float* __restrict__ bbin,
                                              float* __restrict__ ws,
                                              float* __restrict__ out)
{
    int b = blockIdx.x, tid = threadIdx.x;
    const float* lstm = ws + LSTM_OFF;
    __shared__ float m_lds[400];
    float a0 = 0.f, a1 = 0.f;
#pragma unroll 4
    for (int t = 0; t < TLEN; t++) {
        const float* rowp = lstm + ((size_t)t * BATCH + b) * 400;
        a0 += rowp[tid];
        if (tid < 144) a1 += rowp[256 + tid];
    }
    m_lds[tid] = a0 * (1.f / 512.f);
    if (tid < 144) m_lds[256 + tid] = a1 * (1.f / 512.f);
    __syncthreads();
    int wv = tid >> 6, lane = tid & 63;
    if (wv < 2) {
        float p = 0.f;
        for (int j = lane; j < 400; j += 64) p += m_lds[j] * Wbin[wv * 400 + j];
#pragma unroll
        for (int off = 32; off > 0; off >>= 1) p += __shfl_down(p, off);
        if (lane == 0) out[(size_t)BATCH * TLEN + b * 2 + wv] = p + bbin[wv];
    }
}

// ---------------- K5: masked Viterbi decode + traceback ----------------
__global__ __launch_bounds__(64) void k5_vit(const int* __restrict__ masks,
                                             const float* __restrict__ trans,
                                             const float* __restrict__ startv,
                                             const float* __restrict__ endv,
                                             const float* __restrict__ ws,
                                             float* __restrict__ out)
{
    int b = blockIdx.x, lane = threadIdx.x;
    const float* em = ws + EM_OFF;
    __shared__ float emlds[TLEN * KTAG];
    __shared__ unsigned char bpl[TLEN * KTAG];
    __shared__ int mlds[TLEN];
    __shared__ unsigned char tagl[TLEN];
    __shared__ float slds[KTAG];
    __shared__ float fin[KTAG];

    for (int idx = lane; idx < TLEN * KTAG; idx += 64) {
        int tt = idx / KTAG, j = idx - tt * KTAG;
        emlds[idx] = em[((size_t)tt * BATCH + b) * KTAG + j];
    }
    for (int idx = lane; idx < TLEN; idx += 64) mlds[idx] = masks[(size_t)b * TLEN + idx];
    bool on = lane < KTAG;
    float tr[KTAG];
    if (on) {
#pragma unroll
        for (int i = 0; i < KTAG; i++) tr[i] = trans[i * KTAG + lane];
    }
    __syncthreads();
    float sown = 0.f;
    if (on) { sown = startv[lane] + emlds[lane]; slds[lane] = sown; }
    __syncthreads();
#pragma unroll 1
    for (int t = 1; t < TLEN; t++) {
        int m = mlds[t];
        float ns = sown; int idx = lane;
        if (on) {
            float best = -3.4e38f; int bi = 0;
#pragma unroll
            for (int i = 0; i < KTAG; i++) {
                float vv = slds[i] + tr[i];
                if (vv > best) { best = vv; bi = i; }   // strict > => first max (matches jnp.argmax)
            }
            if (m != 0) { ns = best + emlds[t * KTAG + lane]; idx = bi; }
        }
        __syncthreads();
        if (on) { sown = ns; slds[lane] = ns; bpl[t * KTAG + lane] = (unsigned char)idx; }
        __syncthreads();
    }
    if (on) fin[lane] = sown + endv[lane];
    __syncthreads();
    if (lane == 0) {
        float bb = -3.4e38f; int bi = 0;
#pragma unroll
        for (int i = 0; i < KTAG; i++) if (fin[i] > bb) { bb = fin[i]; bi = i; }
        int cur = bi;
        tagl[TLEN - 1] = (unsigned char)cur;
        for (int t = TLEN - 1; t >= 1; t--) {
            cur = bpl[t * KTAG + cur];
            tagl[t - 1] = (unsigned char)cur;
        }
    }
    __syncthreads();
    for (int s = lane; s < TLEN; s += 64) out[(size_t)b * TLEN + s] = (float)tagl[s];
}

extern "C" void kernel_launch(void* const* d_in, const int* in_sizes, int n_in,
                              void* d_out, int out_size, void* d_ws, size_t ws_size,
                              hipStream_t stream)
{
    (void)in_sizes; (void)n_in; (void)out_size; (void)ws_size;
    const int*   sentence = (const int*)d_in[0];
    const int*   masks    = (const int*)d_in[1];
    const float* emb      = (const float*)d_in[2];
    const float* Wih_f    = (const float*)d_in[3];
    const float* Whh_f    = (const float*)d_in[4];
    const float* b_f      = (const float*)d_in[5];
    const float* Wih_b    = (const float*)d_in[6];
    const float* Whh_b    = (const float*)d_in[7];
    const float* b_b      = (const float*)d_in[8];
    const float* W_fc     = (const float*)d_in[9];
    const float* b_fc     = (const float*)d_in[10];
    const float* W_bin    = (const float*)d_in[11];
    const float* b_bin    = (const float*)d_in[12];
    const float* trans    = (const float*)d_in[13];
    const float* startv   = (const float*)d_in[14];
    const float* endv     = (const float*)d_in[15];
    float* ws  = (float*)d_ws;
    float* out = (float*)d_out;

    k0_pack<<<313, 256, 0, stream>>>(Whh_f, Whh_b, ws);
    k1_proj<<<626, 256, 0, stream>>>(emb, Wih_f, Wih_b, ws);
    k2_lstm<<<64, 512, 0, stream>>>(sentence, b_f, b_b, ws);
    k3_em<<<4370, 256, 0, stream>>>(W_fc, b_fc, ws);
    k4_bin<<<128, 256, 0, stream>>>(W_bin, b_bin, ws, out);
    k5_vit<<<128, 64, 0, stream>>>(masks, trans, startv, endv, ws, out);
}